// Round 12
// baseline (343.725 us; speedup 1.0000x reference)
//
#include <hip/hip_runtime.h>
#include <hip/hip_bf16.h>
#include <stdint.h>
#include <stddef.h>

#define B_ 8
#define N_ 8192
#define S_ 2048
#define D_ 256
#define C_ 512
#define K_ 512
#define M_ (B_*N_)

typedef __attribute__((ext_vector_type(8))) short bf16x8;
typedef __attribute__((ext_vector_type(4))) float f32x4;
typedef __attribute__((ext_vector_type(4))) short short4v;
typedef __attribute__((ext_vector_type(4))) unsigned int u32x4;

__device__ __forceinline__ short f2b(float f){
  uint32_t u = __builtin_bit_cast(uint32_t, f);
  u += 0x7fffu + ((u >> 16) & 1u);
  return (short)(u >> 16);
}
__device__ __forceinline__ float b2f(short s){
  uint32_t u = ((uint32_t)(uint16_t)s) << 16;
  return __builtin_bit_cast(float, u);
}

typedef const void __attribute__((address_space(1))) gvoid_t;
typedef void __attribute__((address_space(3))) lvoid_t;
__device__ __forceinline__ void gload_lds16(const void* g, void* l){
  __builtin_amdgcn_global_load_lds((gvoid_t*)g, (lvoid_t*)l, 16, 0, 0);
}
#define SBAR()  __builtin_amdgcn_s_barrier()
#define SCHED() __builtin_amdgcn_sched_barrier(0)

// ---------------- W f32 -> bf16 ----------------
__global__ __launch_bounds__(256) void k_wcast(const float* __restrict__ W1,
                                               const float* __restrict__ W2,
                                               short* __restrict__ W1b,
                                               short* __restrict__ W2b){
  int i = blockIdx.x * 256 + threadIdx.x;
  if (i < C_*K_){ W1b[i] = f2b(W1[i]); W2b[i] = f2b(W2[i]); }
}

// ---------------- points2 [B][D][S] -> p2T [B][S][D] (bf16) ----------------
__global__ __launch_bounds__(256) void k_tr_p2(const float* __restrict__ in,
                                               short* __restrict__ out){
  __shared__ float t[64][65];
  int b = blockIdx.z;
  int s0 = blockIdx.x * 64, d0 = blockIdx.y * 64;
  int tid = threadIdx.x;
  const float* ip = in + (size_t)b * D_ * S_;
  #pragma unroll
  for (int i = 0; i < 16; ++i){
    int dd = (tid >> 6) + i*4, ss = tid & 63;
    t[dd][ss] = ip[(size_t)(d0+dd)*S_ + s0+ss];
  }
  __syncthreads();
  short* op = out + (size_t)b * S_ * D_;
  #pragma unroll
  for (int i = 0; i < 16; ++i){
    int ss = (tid >> 6) + i*4, dd = tid & 63;
    op[(size_t)(s0+ss)*D_ + d0+dd] = f2b(t[dd][ss]);
  }
}

// ---------------- points1 [B][D][N] -> A[:, 0:256] (bf16, row stride 512) ----------------
__global__ __launch_bounds__(256) void k_tr_p1(const float* __restrict__ in,
                                               short* __restrict__ A){
  __shared__ float t[64][65];
  int b = blockIdx.z;
  int n0 = blockIdx.x * 64, d0 = blockIdx.y * 64;
  int tid = threadIdx.x;
  const float* ip = in + (size_t)b * D_ * N_;
  #pragma unroll
  for (int i = 0; i < 16; ++i){
    int dd = (tid >> 6) + i*4, nn = tid & 63;
    t[dd][nn] = ip[(size_t)(d0+dd)*N_ + n0+nn];
  }
  __syncthreads();
  short* op = A + ((size_t)(b*N_ + n0)) * 512 + d0;
  #pragma unroll
  for (int i = 0; i < 16; ++i){
    int nn = (tid >> 6) + i*4, dd = tid & 63;
    op[(size_t)nn * 512 + dd] = f2b(t[dd][nn]);
  }
}

// ---------------- 3-NN interpolation -> A[:, 256:512] (bf16) ----------------
__global__ __launch_bounds__(256) void k_interp(const float* __restrict__ xyz1,
                                                const float* __restrict__ xyz2,
                                                const short* __restrict__ p2T,
                                                short* __restrict__ Aout){
  __shared__ float4 cand[S_];          // 32 KB
  __shared__ float  part[3][64][4];    // partial top-4 keys from waves 1..3
  __shared__ float  wres[3][64];
  __shared__ int    ires[3][64];

  const int b   = blockIdx.y;
  const int n0  = blockIdx.x * 64;
  const int tid = threadIdx.x;

  const float* xz2 = xyz2 + (size_t)b * 3 * S_;
  for (int i = tid; i < S_; i += 256){
    float4 c;
    c.x = xz2[i]; c.y = xz2[S_ + i]; c.z = xz2[2*S_ + i]; c.w = 0.f;
    cand[i] = c;
  }
  __syncthreads();

  const int h = tid >> 6;        // wave id 0..3 (wave-uniform)
  const int q = tid & 63;
  const int n = n0 + q;
  const float* xz1 = xyz1 + (size_t)b * 3 * N_;
  const float x1 = xz1[n], y1 = xz1[N_ + n], z1 = xz1[2*N_ + n];

  const float INF = __builtin_inff();
  float t0 = INF, t1 = INF, t2 = INF, t3 = INF;
  const int sbase = h << 9;

  #pragma unroll 8
  for (int j = 0; j < 512; ++j){
    int s = sbase + j;
    float4 c = cand[s];
    float dx = x1 - c.x, dy = y1 - c.y, dz = z1 - c.z;
    float d = fmaf(dx, dx, fmaf(dy, dy, dz*dz));
    uint32_t kb = (__builtin_bit_cast(uint32_t, d) & ~2047u) | (uint32_t)s;
    float m = __builtin_bit_cast(float, kb);
    float a;
    a = fminf(t0, m); m = fmaxf(t0, m); t0 = a;
    a = fminf(t1, m); m = fmaxf(t1, m); t1 = a;
    a = fminf(t2, m); m = fmaxf(t2, m); t2 = a;
    t3 = fminf(t3, m);
  }

  if (h){
    part[h-1][q][0] = t0; part[h-1][q][1] = t1;
    part[h-1][q][2] = t2; part[h-1][q][3] = t3;
  }
  __syncthreads();

  if (!h){
    #pragma unroll
    for (int r = 0; r < 3; ++r){
      #pragma unroll
      for (int k = 0; k < 4; ++k){
        float m = part[r][q][k];
        float a;
        a = fminf(t0, m); m = fmaxf(t0, m); t0 = a;
        a = fminf(t1, m); m = fmaxf(t1, m); t1 = a;
        a = fminf(t2, m); m = fmaxf(t2, m); t2 = a;
        t3 = fminf(t3, m);
      }
    }
    int ci[4];
    ci[0] = (int)(__builtin_bit_cast(uint32_t, t0) & 2047u);
    ci[1] = (int)(__builtin_bit_cast(uint32_t, t1) & 2047u);
    ci[2] = (int)(__builtin_bit_cast(uint32_t, t2) & 2047u);
    ci[3] = (int)(__builtin_bit_cast(uint32_t, t3) & 2047u);
    // f64 refinement of the 4 survivors (np-grade selection + weights)
    double dd[4];
    const double xd = (double)x1, yd = (double)y1, zd = (double)z1;
    #pragma unroll
    for (int r = 0; r < 4; ++r){
      float4 c = cand[ci[r]];
      double ex = xd - (double)c.x;
      double ey = yd - (double)c.y;
      double ez = zd - (double)c.z;
      dd[r] = ex*ex + ey*ey + ez*ez;
    }
    #pragma unroll
    for (int a2 = 0; a2 < 3; ++a2)
      #pragma unroll
      for (int b2 = a2 + 1; b2 < 4; ++b2)
        if (dd[b2] < dd[a2] || (dd[b2] == dd[a2] && ci[b2] < ci[a2])){
          double td = dd[a2]; dd[a2] = dd[b2]; dd[b2] = td;
          int ti = ci[a2]; ci[a2] = ci[b2]; ci[b2] = ti;
        }
    double r0 = 1.0/(dd[0] + 1e-8), r1 = 1.0/(dd[1] + 1e-8), r2 = 1.0/(dd[2] + 1e-8);
    double rs = r0 + r1 + r2;
    wres[0][q] = (float)(r0/rs); wres[1][q] = (float)(r1/rs); wres[2][q] = (float)(r2/rs);
    ires[0][q] = ci[0]; ires[1][q] = ci[1]; ires[2][q] = ci[2];
  }
  __syncthreads();

  // wave-cooperative gather: 4 waves x 16 queries, 512B coalesced bf16 rows
  const int lane = tid & 63;
  for (int qq = 0; qq < 16; ++qq){
    int q2 = (h << 4) + qq;
    int i0 = ires[0][q2], i1 = ires[1][q2], i2 = ires[2][q2];
    float w0 = wres[0][q2], w1 = wres[1][q2], w2 = wres[2][q2];
    const short4v* P0 = (const short4v*)(p2T + ((size_t)b*S_ + i0) * D_ + (lane << 2));
    const short4v* P1 = (const short4v*)(p2T + ((size_t)b*S_ + i1) * D_ + (lane << 2));
    const short4v* P2 = (const short4v*)(p2T + ((size_t)b*S_ + i2) * D_ + (lane << 2));
    short4v a0 = *P0, a1 = *P1, a2 = *P2;
    short4v st;
    #pragma unroll
    for (int e = 0; e < 4; ++e)
      st[e] = f2b(w0*b2f(a0[e]) + w1*b2f(a1[e]) + w2*b2f(a2[e]));
    *(short4v*)(Aout + ((size_t)(b*N_ + n0 + q2)) * 512 + 256 + (lane << 2)) = st;
  }
}

// ---------------- GEMM1: LDS-free direct-fragment MFMA ----------------
// 1 wave/block, 64x64 output tile, zero LDS / zero barriers. MFMA fragments
// are loaded straight from global: lane (q4,l15) reads 16B at
// row+l15, k = kt*32 + q4*8 -> a wave covers 16 rows x 64B contiguous
// segments (coalesced at 64B granularity; both kt parities share a 128B
// line). W (512 KB) is L2-resident; A streams from HBM once; redundant
// cross-block reads hit L2/L3. No sync structure -> compiler pipelines
// loads across MFMAs freely (no vmcnt(0)-at-barrier drain).
__global__ __launch_bounds__(64, 3) void k_gemm_d(const short* __restrict__ A,
                                                  const short* __restrict__ W,
                                                  const float* __restrict__ bias,
                                                  short* __restrict__ Y,
                                                  float* __restrict__ psum,
                                                  float* __restrict__ psq){
  int bid = blockIdx.x;
  int sw = ((bid & 7) << 10) | (bid >> 3);   // 8192 blocks, bijective XCD swizzle
  int mblk = sw >> 3, nblk = sw & 7;         // nblk fastest -> A-tile L2 reuse
  int m0 = mblk << 6, ncol0 = nblk << 6;
  int lane = threadIdx.x & 63;
  int l15 = lane & 15, q4 = lane >> 4;
  const short* Ab = A + (size_t)(m0    + l15) * K_ + (q4 << 3);
  const short* Bb = W + (size_t)(ncol0 + l15) * K_ + (q4 << 3);

  f32x4 acc[4][4];
  #pragma unroll
  for (int m = 0; m < 4; ++m)
    #pragma unroll
    for (int n = 0; n < 4; ++n) acc[m][n] = (f32x4){0.f,0.f,0.f,0.f};

  #pragma unroll 4
  for (int kt = 0; kt < K_/32; ++kt){
    bf16x8 af[4], bf[4];
    #pragma unroll
    for (int m = 0; m < 4; ++m)
      af[m] = *(const bf16x8*)(Ab + (size_t)(m << 4) * K_ + kt*32);
    #pragma unroll
    for (int n = 0; n < 4; ++n)
      bf[n] = *(const bf16x8*)(Bb + (size_t)(n << 4) * K_ + kt*32);
    #pragma unroll
    for (int m = 0; m < 4; ++m)
      #pragma unroll
      for (int n = 0; n < 4; ++n)
        acc[m][n] = __builtin_amdgcn_mfma_f32_16x16x32_bf16(af[m], bf[n], acc[m][n], 0, 0, 0);
  }

  // epilogue: bias, bf16 store, per-column stats (C/D: col=lane&15, row=q4*4+j)
  #pragma unroll
  for (int n = 0; n < 4; ++n){
    int col = ncol0 + (n << 4) + l15;
    float bv = bias[col];
    float s = 0.f, q = 0.f;
    #pragma unroll
    for (int m = 0; m < 4; ++m){
      int rbase = m0 + (m << 4) + (q4 << 2);
      #pragma unroll
      for (int j = 0; j < 4; ++j){
        float v = acc[m][n][j] + bv;
        Y[(size_t)(rbase + j) * C_ + col] = f2b(v);
        s += v; q += v*v;
      }
    }
    s += __shfl_xor(s, 16); s += __shfl_xor(s, 32);
    q += __shfl_xor(q, 16); q += __shfl_xor(q, 32);
    if (lane < 16){
      psum[(size_t)mblk * C_ + ncol0 + (n << 4) + lane] = s;
      psq [(size_t)mblk * C_ + ncol0 + (n << 4) + lane] = q;
    }
  }
}

// ---------------- GEMM2: R10-proven counted-vmcnt dbuf + BN1 APPLY fusion ----------------
template<int APPLY>
__global__ __launch_bounds__(256) void k_gemm_t(const short* __restrict__ A,
                                                const short* __restrict__ W,
                                                const float* __restrict__ bias,
                                                const float* __restrict__ ascale,
                                                const float* __restrict__ ashift,
                                                short* __restrict__ Y,
                                                float* __restrict__ psum,
                                                float* __restrict__ psq){
  __shared__ short As[2][128*64];      // 2 x 16 KB
  __shared__ short Bs[2][128*64];      // 2 x 16 KB
  __shared__ float ssum[2][128];
  __shared__ float ssq[2][128];
  __shared__ float sls[APPLY ? K_ : 1];
  __shared__ float shs[APPLY ? K_ : 1];
  int bid = blockIdx.x;
  int sw = ((bid & 7) << 8) + (bid >> 3);      // XCD swizzle, 2048 % 8 == 0 -> bijective
  int mblk = sw >> 2, nblk = sw & 3;
  int m0 = mblk * 128, ncol0 = nblk * 128;
  int tid = threadIdx.x, wv = tid >> 6, lane = tid & 63;
  int wr = wv >> 1, wc = wv & 1;

  if constexpr (APPLY){
    sls[tid]       = ascale[tid];
    sls[tid + 256] = ascale[tid + 256];
    shs[tid]       = ashift[tid];
    shs[tid + 256] = ashift[tid + 256];
  }
  // R7 race fix: sls/shs are read cross-wave by the prologue's writeA.
  __syncthreads();

  f32x4 acc[4][4];
  #pragma unroll
  for (int m = 0; m < 4; ++m)
    #pragma unroll
    for (int n = 0; n < 4; ++n) acc[m][n] = (f32x4){0.f,0.f,0.f,0.f};

  int r8 = lane >> 3;
  int c8 = (lane & 7) ^ r8;                    // inverse-swizzled source chunk
  const short* Ap = A + (size_t)(m0    + (wv << 3) + r8) * K_ + (c8 << 3);
  const short* Bp = W + (size_t)(ncol0 + (wv << 3) + r8) * K_ + (c8 << 3);

  int l15 = lane & 15, q4 = lane >> 4, low3 = lane & 7;
  int ck0 = (q4 ^ low3) << 3;                  // kk=0
  int ck1 = ((4 | q4) ^ low3) << 3;            // kk=1

  auto stageB = [&](int buf, int kt){
    short* dst = &Bs[buf][(wv << 9)];
    const short* src = Bp + kt*64;
    #pragma unroll
    for (int i = 0; i < 4; ++i) gload_lds16(src + i*32*K_, dst + (i << 11));
  };
  auto stageA_g = [&](int buf, int kt){
    short* dst = &As[buf][(wv << 9)];
    const short* src = Ap + kt*64;
    #pragma unroll
    for (int i = 0; i < 4; ++i) gload_lds16(src + i*32*K_, dst + (i << 11));
  };
  auto loadA = [&](int kt, bf16x8* av){
    const short* src = Ap + kt*64;
    #pragma unroll
    for (int i = 0; i < 4; ++i) av[i] = *(const bf16x8*)(src + i*32*K_);
  };
  auto writeA = [&](int buf, int kt, const bf16x8* av){
    int c0 = kt*64 + (c8 << 3);
    float4 scl = *(const float4*)&sls[c0];
    float4 sch = *(const float4*)&sls[c0 + 4];
    float4 shl = *(const float4*)&shs[c0];
    float4 shh = *(const float4*)&shs[c0 + 4];
    float sc[8] = {scl.x, scl.y, scl.z, scl.w, sch.x, sch.y, sch.z, sch.w};
    float sh[8] = {shl.x, shl.y, shl.z, shl.w, shh.x, shh.y, shh.z, shh.w};
    short* wdst = &As[buf][(wv << 9) + (lane << 3)];
    #pragma unroll
    for (int i = 0; i < 4; ++i){
      u32x4 pk;
      #pragma unroll
      for (int j = 0; j < 4; ++j){
        float lo = fmaxf(fmaf(b2f(av[i][2*j]),   sc[2*j],   sh[2*j]),   0.f);
        float hi = fmaxf(fmaf(b2f(av[i][2*j+1]), sc[2*j+1], sh[2*j+1]), 0.f);
        uint32_t t;
        asm("v_cvt_pk_bf16_f32 %0, %1, %2" : "=v"(t) : "v"(lo), "v"(hi));
        pk[j] = t;
      }
      *(u32x4*)(wdst + (i << 11)) = pk;
    }
  };
  auto compute = [&](int buf){
    #pragma unroll
    for (int kk = 0; kk < 2; ++kk){
      int ck = kk ? ck1 : ck0;
      bf16x8 af[4], bfr[4];
      #pragma unroll
      for (int m = 0; m < 4; ++m)
        af[m] = *(const bf16x8*)(&As[buf][((wr << 6) + (m << 4) + l15)*64 + ck]);
      #pragma unroll
      for (int n = 0; n < 4; ++n)
        bfr[n] = *(const bf16x8*)(&Bs[buf][((wc << 6) + (n << 4) + l15)*64 + ck]);
      #pragma unroll
      for (int m = 0; m < 4; ++m)
        #pragma unroll
        for (int n = 0; n < 4; ++n)
          acc[m][n] = __builtin_amdgcn_mfma_f32_16x16x32_bf16(af[m], bfr[n], acc[m][n], 0, 0, 0);
    }
  };

  // prologue
  if constexpr (APPLY){
    bf16x8 av[4];
    loadA(0, av);
    stageB(0, 0);
    writeA(0, 0, av);
    asm volatile("s_waitcnt lgkmcnt(0)" ::: "memory");
    SCHED();
  } else {
    stageA_g(0, 0);
    stageB(0, 0);
  }

  int cur = 0;
  for (int kt = 0; kt < K_/64 - 1; ++kt){
    if constexpr (APPLY){
      bf16x8 av[4];
      loadA(kt + 1, av);
      stageB(cur ^ 1, kt + 1);
      asm volatile("s_waitcnt vmcnt(8)" ::: "memory");
      SCHED();
      SBAR();
      SCHED();
      compute(cur);
      writeA(cur ^ 1, kt + 1, av);
      asm volatile("s_waitcnt lgkmcnt(0)" ::: "memory");
      SCHED();
      SBAR();
      SCHED();
    } else {
      stageA_g(cur ^ 1, kt + 1);
      stageB(cur ^ 1, kt + 1);
      asm volatile("s_waitcnt vmcnt(8)" ::: "memory");
      SCHED();
      SBAR();
      SCHED();
      compute(cur);
      SCHED();
      SBAR();
      SCHED();
    }
    cur ^= 1;
  }
  asm volatile("s_waitcnt vmcnt(0) lgkmcnt(0)" ::: "memory");
  SCHED();
  SBAR();
  SCHED();
  compute(cur);

  int rbase = m0 + (wr << 6) + ((lane >> 4) << 2);
  int cbase = ncol0 + (wc << 6) + l15;
  #pragma unroll
  for (int n = 0; n < 4; ++n){
    int col = cbase + (n << 4);
    float bv = bias[col];
    float s = 0.f, q = 0.f;
    #pragma unroll
    for (int m = 0; m < 4; ++m){
      #pragma unroll
      for (int j = 0; j < 4; ++j){
        float v = acc[m][n][j] + bv;
        Y[(size_t)(rbase + (m << 4) + j) * C_ + col] = f2b(v);
        s += v; q += v*v;
      }
    }
    s += __shfl_xor(s, 16); s += __shfl_xor(s, 32);
    q += __shfl_xor(q, 16); q += __shfl_xor(q, 32);
    if (lane < 16){
      ssum[wr][(wc << 6) + (n << 4) + lane] = s;
      ssq [wr][(wc << 6) + (n << 4) + lane] = q;
    }
  }
  __syncthreads();
  if (tid < 128){
    psum[(size_t)mblk * C_ + ncol0 + tid] = ssum[0][tid] + ssum[1][tid];
    psq [(size_t)mblk * C_ + ncol0 + tid] = ssq [0][tid] + ssq [1][tid];
  }
}

// ---------------- stats finalize: deterministic reduce over nmb partials ----------------
__global__ __launch_bounds__(64) void k_stats(const float* __restrict__ psum,
                                              const float* __restrict__ psq,
                                              int nmb,
                                              const float* __restrict__ g,
                                              const float* __restrict__ be,
                                              float* __restrict__ scale,
                                              float* __restrict__ shift){
  int ch = blockIdx.x;
  int lane = threadIdx.x;
  float s = 0.f, q = 0.f;
  for (int mb = lane; mb < nmb; mb += 64){
    s += psum[(size_t)mb * C_ + ch];
    q += psq [(size_t)mb * C_ + ch];
  }
  #pragma unroll
  for (int off = 1; off < 64; off <<= 1){
    s += __shfl_xor(s, off);
    q += __shfl_xor(q, off);
  }
  if (lane == 0){
    const float invM = 1.0f / (float)M_;
    float mean = s * invM;
    float var  = q * invM - mean * mean;
    float sc = g[ch] / sqrtf(var + 1e-5f);
    scale[ch] = sc;
    shift[ch] = be[ch] - mean * sc;
  }
}

// ---------------- BN apply + ReLU + transpose to out [B][C][N] f32 ----------------
__global__ __launch_bounds__(256) void k_out(const short* __restrict__ Y2,
                                             const float* __restrict__ scale,
                                             const float* __restrict__ shift,
                                             float* __restrict__ out){
  __shared__ float t[64][65];
  int r0 = blockIdx.x * 64;
  int c0 = blockIdx.y * 64;
  int tid = threadIdx.x;
  #pragma unroll
  for (int i = 0; i < 4; ++i){
    int rr = (tid >> 4) + i*16, cc = (tid & 15) << 2;
    short4v v = *(const short4v*)(Y2 + (size_t)(r0 + rr) * C_ + c0 + cc);
    t[rr][cc]   = b2f(v[0]);
    t[rr][cc+1] = b2f(v[1]);
    t[rr][cc+2] = b2f(v[2]);
    t[rr][cc+3] = b2f(v[3]);
  }
  __syncthreads();
  int b = r0 >> 13, nb = r0 & (N_ - 1);
  #pragma unroll
  for (int i = 0; i < 16; ++i){
    int cc = (tid >> 6) + i*4, nn = tid & 63;
    int c = c0 + cc;
    float v = fmaf(t[nn][cc], scale[c], shift[c]);
    out[((size_t)b * C_ + c) * N_ + nb + nn] = fmaxf(v, 0.f);
  }
}

extern "C" void kernel_launch(void* const* d_in, const int* in_sizes, int n_in,
                              void* d_out, int out_size, void* d_ws, size_t ws_size,
                              hipStream_t stream){
  const float* xyz1    = (const float*)d_in[0];
  const float* xyz2    = (const float*)d_in[1];
  const float* points1 = (const float*)d_in[2];
  const float* points2 = (const float*)d_in[3];
  const float* W1  = (const float*)d_in[4];
  const float* b1  = (const float*)d_in[5];
  const float* g1  = (const float*)d_in[6];
  const float* be1 = (const float*)d_in[7];
  const float* W2  = (const float*)d_in[8];
  const float* b2  = (const float*)d_in[9];
  const float* g2  = (const float*)d_in[10];
  const float* be2 = (const float*)d_in[11];
  float* out = (float*)d_out;

  char* ws = (char*)d_ws;
  size_t off = 0;
  auto alloc = [&](size_t bytes) -> void* {
    void* p = ws + off;
    off += (bytes + 255) & ~(size_t)255;
    return p;
  };
  short* p2Tb   = (short*)alloc((size_t)B_*S_*D_*2);   // 8 MB (bf16)
  short* Abuf   = (short*)alloc((size_t)M_*C_*2);      // 64 MB (new_points)
  short* y1     = (short*)alloc((size_t)M_*C_*2);      // 64 MB
  short* y2     = (short*)alloc((size_t)M_*C_*2);      // 64 MB
  short* W1b    = (short*)alloc((size_t)C_*K_*2);
  short* W2b    = (short*)alloc((size_t)C_*K_*2);
  float* psum   = (float*)alloc((size_t)(M_/64)*C_*4); // 2 MB
  float* psq    = (float*)alloc((size_t)(M_/64)*C_*4); // 2 MB
  float* scale1 = (float*)alloc(C_*4);
  float* shift1 = (float*)alloc(C_*4);
  float* scale2 = (float*)alloc(C_*4);
  float* shift2 = (float*)alloc(C_*4);
  (void)ws_size; (void)in_sizes; (void)n_in; (void)out_size;

  k_wcast <<<dim3((C_*K_ + 255)/256), 256, 0, stream>>>(W1, W2, W1b, W2b);
  k_tr_p2 <<<dim3(S_/64, D_/64, B_), 256, 0, stream>>>(points2, p2Tb);
  k_tr_p1 <<<dim3(N_/64, D_/64, B_), 256, 0, stream>>>(points1, Abuf);
  k_interp<<<dim3(N_/64, B_), 256, 0, stream>>>(xyz1, xyz2, p2Tb, Abuf);
  k_gemm_d<<<dim3((M_/64)*(C_/64)), 64, 0, stream>>>(Abuf, W1b, b1, y1, psum, psq);
  k_stats <<<dim3(C_), 64, 0, stream>>>(psum, psq, M_/64, g1, be1, scale1, shift1);
  k_gemm_t<1><<<dim3((M_/128)*(C_/128)), 256, 0, stream>>>(y1, W2b, b2, scale1, shift1, y2, psum, psq);
  k_stats <<<dim3(C_), 64, 0, stream>>>(psum, psq, M_/128, g2, be2, scale2, shift2);
  k_out   <<<dim3(M_/64, C_/64), 256, 0, stream>>>(y2, scale2, shift2, out);
}

// Round 13
// 268.004 us; speedup vs baseline: 1.2825x; 1.2825x over previous
//
#include <hip/hip_runtime.h>
#include <hip/hip_bf16.h>
#include <stdint.h>
#include <stddef.h>

#define B_ 8
#define N_ 8192
#define S_ 2048
#define D_ 256
#define C_ 512
#define K_ 512
#define M_ (B_*N_)

typedef __attribute__((ext_vector_type(8))) short bf16x8;
typedef __attribute__((ext_vector_type(4))) float f32x4;
typedef __attribute__((ext_vector_type(4))) short short4v;
typedef __attribute__((ext_vector_type(4))) unsigned int u32x4;

__device__ __forceinline__ short f2b(float f){
  uint32_t u = __builtin_bit_cast(uint32_t, f);
  u += 0x7fffu + ((u >> 16) & 1u);
  return (short)(u >> 16);
}
__device__ __forceinline__ float b2f(short s){
  uint32_t u = ((uint32_t)(uint16_t)s) << 16;
  return __builtin_bit_cast(float, u);
}

typedef const void __attribute__((address_space(1))) gvoid_t;
typedef void __attribute__((address_space(3))) lvoid_t;
__device__ __forceinline__ void gload_lds16(const void* g, void* l){
  __builtin_amdgcn_global_load_lds((gvoid_t*)g, (lvoid_t*)l, 16, 0, 0);
}

// ---------------- W f32 -> bf16 ----------------
__global__ __launch_bounds__(256) void k_wcast(const float* __restrict__ W1,
                                               const float* __restrict__ W2,
                                               short* __restrict__ W1b,
                                               short* __restrict__ W2b){
  int i = blockIdx.x * 256 + threadIdx.x;
  if (i < C_*K_){ W1b[i] = f2b(W1[i]); W2b[i] = f2b(W2[i]); }
}

// ---------------- points2 [B][D][S] -> p2T [B][S][D] (bf16) ----------------
__global__ __launch_bounds__(256) void k_tr_p2(const float* __restrict__ in,
                                               short* __restrict__ out){
  __shared__ float t[64][65];
  int b = blockIdx.z;
  int s0 = blockIdx.x * 64, d0 = blockIdx.y * 64;
  int tid = threadIdx.x;
  const float* ip = in + (size_t)b * D_ * S_;
  #pragma unroll
  for (int i = 0; i < 16; ++i){
    int dd = (tid >> 6) + i*4, ss = tid & 63;
    t[dd][ss] = ip[(size_t)(d0+dd)*S_ + s0+ss];
  }
  __syncthreads();
  short* op = out + (size_t)b * S_ * D_;
  #pragma unroll
  for (int i = 0; i < 16; ++i){
    int ss = (tid >> 6) + i*4, dd = tid & 63;
    op[(size_t)(s0+ss)*D_ + d0+dd] = f2b(t[dd][ss]);
  }
}

// ---------------- points1 [B][D][N] -> A[:, 0:256] (bf16, row stride 512) ----------------
__global__ __launch_bounds__(256) void k_tr_p1(const float* __restrict__ in,
                                               short* __restrict__ A){
  __shared__ float t[64][65];
  int b = blockIdx.z;
  int n0 = blockIdx.x * 64, d0 = blockIdx.y * 64;
  int tid = threadIdx.x;
  const float* ip = in + (size_t)b * D_ * N_;
  #pragma unroll
  for (int i = 0; i < 16; ++i){
    int dd = (tid >> 6) + i*4, nn = tid & 63;
    t[dd][nn] = ip[(size_t)(d0+dd)*N_ + n0+nn];
  }
  __syncthreads();
  short* op = A + ((size_t)(b*N_ + n0)) * 512 + d0;
  #pragma unroll
  for (int i = 0; i < 16; ++i){
    int nn = (tid >> 6) + i*4, dd = tid & 63;
    op[(size_t)nn * 512 + dd] = f2b(t[dd][nn]);
  }
}

// ---------------- 3-NN interpolation -> A[:, 256:512] (bf16) ----------------
// Split candidate arrays (24 KB vs 32 KB float4) -> 5 blocks/CU (was 4).
__global__ __launch_bounds__(256) void k_interp(const float* __restrict__ xyz1,
                                                const float* __restrict__ xyz2,
                                                const short* __restrict__ p2T,
                                                short* __restrict__ Aout){
  __shared__ float cx[S_], cy[S_], cz[S_];   // 24 KB
  __shared__ float  part[3][64][4];
  __shared__ float  wres[3][64];
  __shared__ int    ires[3][64];

  const int b   = blockIdx.y;
  const int n0  = blockIdx.x * 64;
  const int tid = threadIdx.x;

  const float* xz2 = xyz2 + (size_t)b * 3 * S_;
  for (int i = tid; i < S_; i += 256){
    cx[i] = xz2[i]; cy[i] = xz2[S_ + i]; cz[i] = xz2[2*S_ + i];
  }
  __syncthreads();

  const int h = tid >> 6;        // wave id 0..3 (wave-uniform)
  const int q = tid & 63;
  const int n = n0 + q;
  const float* xz1 = xyz1 + (size_t)b * 3 * N_;
  const float x1 = xz1[n], y1 = xz1[N_ + n], z1 = xz1[2*N_ + n];

  const float INF = __builtin_inff();
  float t0 = INF, t1 = INF, t2 = INF, t3 = INF;
  const int sbase = h << 9;

  #pragma unroll 8
  for (int j = 0; j < 512; ++j){
    int s = sbase + j;
    float dx = x1 - cx[s], dy = y1 - cy[s], dz = z1 - cz[s];
    float d = fmaf(dx, dx, fmaf(dy, dy, dz*dz));
    uint32_t kb = (__builtin_bit_cast(uint32_t, d) & ~2047u) | (uint32_t)s;
    float m = __builtin_bit_cast(float, kb);
    float a;
    a = fminf(t0, m); m = fmaxf(t0, m); t0 = a;
    a = fminf(t1, m); m = fmaxf(t1, m); t1 = a;
    a = fminf(t2, m); m = fmaxf(t2, m); t2 = a;
    t3 = fminf(t3, m);
  }

  if (h){
    part[h-1][q][0] = t0; part[h-1][q][1] = t1;
    part[h-1][q][2] = t2; part[h-1][q][3] = t3;
  }
  __syncthreads();

  if (!h){
    #pragma unroll
    for (int r = 0; r < 3; ++r){
      #pragma unroll
      for (int k = 0; k < 4; ++k){
        float m = part[r][q][k];
        float a;
        a = fminf(t0, m); m = fmaxf(t0, m); t0 = a;
        a = fminf(t1, m); m = fmaxf(t1, m); t1 = a;
        a = fminf(t2, m); m = fmaxf(t2, m); t2 = a;
        t3 = fminf(t3, m);
      }
    }
    int ci[4];
    ci[0] = (int)(__builtin_bit_cast(uint32_t, t0) & 2047u);
    ci[1] = (int)(__builtin_bit_cast(uint32_t, t1) & 2047u);
    ci[2] = (int)(__builtin_bit_cast(uint32_t, t2) & 2047u);
    ci[3] = (int)(__builtin_bit_cast(uint32_t, t3) & 2047u);
    // f64 refinement of the 4 survivors (np-grade selection + weights)
    double dd[4];
    const double xd = (double)x1, yd = (double)y1, zd = (double)z1;
    #pragma unroll
    for (int r = 0; r < 4; ++r){
      int s = ci[r];
      double ex = xd - (double)cx[s];
      double ey = yd - (double)cy[s];
      double ez = zd - (double)cz[s];
      dd[r] = ex*ex + ey*ey + ez*ez;
    }
    #pragma unroll
    for (int a2 = 0; a2 < 3; ++a2)
      #pragma unroll
      for (int b2 = a2 + 1; b2 < 4; ++b2)
        if (dd[b2] < dd[a2] || (dd[b2] == dd[a2] && ci[b2] < ci[a2])){
          double td = dd[a2]; dd[a2] = dd[b2]; dd[b2] = td;
          int ti = ci[a2]; ci[a2] = ci[b2]; ci[b2] = ti;
        }
    double r0 = 1.0/(dd[0] + 1e-8), r1 = 1.0/(dd[1] + 1e-8), r2 = 1.0/(dd[2] + 1e-8);
    double rs = r0 + r1 + r2;
    wres[0][q] = (float)(r0/rs); wres[1][q] = (float)(r1/rs); wres[2][q] = (float)(r2/rs);
    ires[0][q] = ci[0]; ires[1][q] = ci[1]; ires[2][q] = ci[2];
  }
  __syncthreads();

  // wave-cooperative gather: 4 waves x 16 queries, 512B coalesced bf16 rows
  const int lane = tid & 63;
  for (int qq = 0; qq < 16; ++qq){
    int q2 = (h << 4) + qq;
    int i0 = ires[0][q2], i1 = ires[1][q2], i2 = ires[2][q2];
    float w0 = wres[0][q2], w1 = wres[1][q2], w2 = wres[2][q2];
    const short4v* P0 = (const short4v*)(p2T + ((size_t)b*S_ + i0) * D_ + (lane << 2));
    const short4v* P1 = (const short4v*)(p2T + ((size_t)b*S_ + i1) * D_ + (lane << 2));
    const short4v* P2 = (const short4v*)(p2T + ((size_t)b*S_ + i2) * D_ + (lane << 2));
    short4v a0 = *P0, a1 = *P1, a2 = *P2;
    short4v st;
    #pragma unroll
    for (int e = 0; e < 4; ++e)
      st[e] = f2b(w0*b2f(a0[e]) + w1*b2f(a1[e]) + w2*b2f(a2[e]));
    *(short4v*)(Aout + ((size_t)(b*N_ + n0 + q2)) * 512 + 256 + (lane << 2)) = st;
  }
}

// ---------------- GEMM: Y[m,o] = sum_k A[m,k]*W[o,k] + bias[o]; partial stats ----------------
// R8-proven single-buffer structure: BK=64 [128][64] tiles, 3-bit XOR swizzle
// (linear LDS dest + inverse-swizzled global source for global_load_lds, same
// XOR on ds_read — rule #21). APPLY=1: BN1+ReLU fused into A staging
// (reg load -> fmaf/fmax -> v_cvt_pk_bf16_f32 -> ds_write at linear lane slot),
// with the R5-proven explicit vmcnt(0)+sched_barrier drain before the barrier.
template<int APPLY>
__global__ __launch_bounds__(256) void k_gemm_t(const short* __restrict__ A,
                                                const short* __restrict__ W,
                                                const float* __restrict__ bias,
                                                const float* __restrict__ ascale,
                                                const float* __restrict__ ashift,
                                                short* __restrict__ Y,
                                                float* __restrict__ psum,
                                                float* __restrict__ psq){
  __shared__ short As[128*64];         // 16 KB
  __shared__ short Bs[128*64];         // 16 KB
  __shared__ float ssum[2][128];
  __shared__ float ssq[2][128];
  __shared__ float sls[APPLY ? K_ : 1];
  __shared__ float shs[APPLY ? K_ : 1];
  int bid = blockIdx.x;
  int sw = ((bid & 7) << 8) + (bid >> 3);      // XCD swizzle, 2048 % 8 == 0 -> bijective
  int mblk = sw >> 2, nblk = sw & 3;
  int m0 = mblk * 128, ncol0 = nblk * 128;
  int tid = threadIdx.x, wv = tid >> 6, lane = tid & 63;
  int wr = wv >> 1, wc = wv & 1;

  if constexpr (APPLY){
    sls[tid]       = ascale[tid];
    sls[tid + 256] = ascale[tid + 256];
    shs[tid]       = ashift[tid];
    shs[tid + 256] = ashift[tid + 256];
  }

  f32x4 acc[4][4];
  #pragma unroll
  for (int m = 0; m < 4; ++m)
    #pragma unroll
    for (int n = 0; n < 4; ++n) acc[m][n] = (f32x4){0.f,0.f,0.f,0.f};

  // staging map: thread (wv,lane), pass i=0..3:
  //   row = i*32 + wv*8 + (lane>>3); src chunk = (lane&7) ^ (lane>>3)
  //   LDS byte = i*4096 + wv*1024 + lane*16  (linear; row-major [128][64])
  int r8 = lane >> 3;
  int c8 = (lane & 7) ^ r8;                    // inverse-swizzled source chunk
  const short* Ap = A + (size_t)(m0   + (wv << 3) + r8) * K_ + (c8 << 3);
  const short* Bp = W + (size_t)(ncol0 + (wv << 3) + r8) * K_ + (c8 << 3);
  short* Asl = As + (wv << 9);                 // + lane*16B implicit
  short* Bsl = Bs + (wv << 9);
  short* Awr = As + (wv << 9) + (lane << 3);   // explicit lane slot for ds_write

  // fragment-read swizzle: want chunk C=(kk*4 | q), q=lane>>4, at row with
  // (row&7)==lane&7 -> read slot chunk C ^ (lane&7)
  int l15 = lane & 15, q4 = lane >> 4, low3 = lane & 7;
  int ck0 = (q4 ^ low3) << 3;                  // kk=0, in elems
  int ck1 = ((4 | q4) ^ low3) << 3;            // kk=1

  for (int kt = 0; kt < K_/64; ++kt){
    __syncthreads();
    const int ko = kt * 64;
    if constexpr (APPLY){
      bf16x8 a0 = *(const bf16x8*)(Ap + ko);
      bf16x8 a1 = *(const bf16x8*)(Ap + 32*K_ + ko);
      bf16x8 a2 = *(const bf16x8*)(Ap + 64*K_ + ko);
      bf16x8 a3 = *(const bf16x8*)(Ap + 96*K_ + ko);
      #pragma unroll
      for (int i = 0; i < 4; ++i)
        gload_lds16(Bp + i*32*K_ + ko, Bsl + (i << 11));
      int c0 = ko + (c8 << 3);
      float4 scl = *(const float4*)&sls[c0];
      float4 sch = *(const float4*)&sls[c0 + 4];
      float4 shl = *(const float4*)&shs[c0];
      float4 shh = *(const float4*)&shs[c0 + 4];
      float sc[8] = {scl.x, scl.y, scl.z, scl.w, sch.x, sch.y, sch.z, sch.w};
      float sh[8] = {shl.x, shl.y, shl.z, shl.w, shh.x, shh.y, shh.z, shh.w};
      bf16x8 av[4] = {a0, a1, a2, a3};
      #pragma unroll
      for (int i = 0; i < 4; ++i){
        u32x4 pk;
        #pragma unroll
        for (int j = 0; j < 4; ++j){
          float lo = fmaxf(fmaf(b2f(av[i][2*j]),   sc[2*j],   sh[2*j]),   0.f);
          float hi = fmaxf(fmaf(b2f(av[i][2*j+1]), sc[2*j+1], sh[2*j+1]), 0.f);
          uint32_t t;
          asm("v_cvt_pk_bf16_f32 %0, %1, %2" : "=v"(t) : "v"(lo), "v"(hi));
          pk[j] = t;
        }
        *(u32x4*)(Awr + (i << 11)) = pk;
      }
      // Drain the global_load_lds LDS writes explicitly before the barrier.
      asm volatile("s_waitcnt vmcnt(0)" ::: "memory");
      __builtin_amdgcn_sched_barrier(0);
    } else {
      #pragma unroll
      for (int i = 0; i < 4; ++i){
        gload_lds16(Ap + i*32*K_ + ko, Asl + (i << 11));
        gload_lds16(Bp + i*32*K_ + ko, Bsl + (i << 11));
      }
    }
    __syncthreads();
    #pragma unroll
    for (int kk = 0; kk < 2; ++kk){
      int ck = kk ? ck1 : ck0;
      bf16x8 af[4], bfr[4];
      #pragma unroll
      for (int m = 0; m < 4; ++m)
        af[m] = *(const bf16x8*)(As + ((wr << 6) + (m << 4) + l15)*64 + ck);
      #pragma unroll
      for (int n = 0; n < 4; ++n)
        bfr[n] = *(const bf16x8*)(Bs + ((wc << 6) + (n << 4) + l15)*64 + ck);
      #pragma unroll
      for (int m = 0; m < 4; ++m)
        #pragma unroll
        for (int n = 0; n < 4; ++n)
          acc[m][n] = __builtin_amdgcn_mfma_f32_16x16x32_bf16(af[m], bfr[n], acc[m][n], 0, 0, 0);
    }
  }

  // epilogue: bias add, bf16 store, per-column partial sums (C/D layout: col=lane&15, row=(lane>>4)*4+reg)
  int rbase = m0 + (wr << 6) + ((lane >> 4) << 2);
  int cbase = ncol0 + (wc << 6) + l15;
  #pragma unroll
  for (int n = 0; n < 4; ++n){
    int col = cbase + (n << 4);
    float bv = bias[col];
    float s = 0.f, q = 0.f;
    #pragma unroll
    for (int m = 0; m < 4; ++m){
      #pragma unroll
      for (int j = 0; j < 4; ++j){
        float v = acc[m][n][j] + bv;
        Y[(size_t)(rbase + (m << 4) + j) * C_ + col] = f2b(v);
        s += v; q += v*v;
      }
    }
    s += __shfl_xor(s, 16); s += __shfl_xor(s, 32);
    q += __shfl_xor(q, 16); q += __shfl_xor(q, 32);
    if (lane < 16){
      ssum[wr][(wc << 6) + (n << 4) + lane] = s;
      ssq [wr][(wc << 6) + (n << 4) + lane] = q;
    }
  }
  __syncthreads();
  if (tid < 128){
    psum[(size_t)mblk * C_ + ncol0 + tid] = ssum[0][tid] + ssum[1][tid];
    psq [(size_t)mblk * C_ + ncol0 + tid] = ssq [0][tid] + ssq [1][tid];
  }
}

// ---------------- stats finalize: deterministic reduce over 512 mblk partials ----------------
__global__ __launch_bounds__(64) void k_stats(const float* __restrict__ psum,
                                              const float* __restrict__ psq,
                                              const float* __restrict__ g,
                                              const float* __restrict__ be,
                                              float* __restrict__ scale,
                                              float* __restrict__ shift){
  int ch = blockIdx.x;
  int lane = threadIdx.x;
  float s = 0.f, q = 0.f;
  for (int mb = lane; mb < M_/128; mb += 64){
    s += psum[(size_t)mb * C_ + ch];
    q += psq [(size_t)mb * C_ + ch];
  }
  #pragma unroll
  for (int off = 1; off < 64; off <<= 1){
    s += __shfl_xor(s, off);
    q += __shfl_xor(q, off);
  }
  if (lane == 0){
    const float invM = 1.0f / (float)M_;
    float mean = s * invM;
    float var  = q * invM - mean * mean;
    float sc = g[ch] / sqrtf(var + 1e-5f);
    scale[ch] = sc;
    shift[ch] = be[ch] - mean * sc;
  }
}

// ---------------- BN apply + ReLU + transpose to out [B][C][N] f32 ----------------
__global__ __launch_bounds__(256) void k_out(const short* __restrict__ Y2,
                                             const float* __restrict__ scale,
                                             const float* __restrict__ shift,
                                             float* __restrict__ out){
  __shared__ float t[64][65];
  int r0 = blockIdx.x * 64;
  int c0 = blockIdx.y * 64;
  int tid = threadIdx.x;
  #pragma unroll
  for (int i = 0; i < 4; ++i){
    int rr = (tid >> 4) + i*16, cc = (tid & 15) << 2;
    short4v v = *(const short4v*)(Y2 + (size_t)(r0 + rr) * C_ + c0 + cc);
    t[rr][cc]   = b2f(v[0]);
    t[rr][cc+1] = b2f(v[1]);
    t[rr][cc+2] = b2f(v[2]);
    t[rr][cc+3] = b2f(v[3]);
  }
  __syncthreads();
  int b = r0 >> 13, nb = r0 & (N_ - 1);
  #pragma unroll
  for (int i = 0; i < 16; ++i){
    int cc = (tid >> 6) + i*4, nn = tid & 63;
    int c = c0 + cc;
    float v = fmaf(t[nn][cc], scale[c], shift[c]);
    out[((size_t)b * C_ + c) * N_ + nb + nn] = fmaxf(v, 0.f);
  }
}

extern "C" void kernel_launch(void* const* d_in, const int* in_sizes, int n_in,
                              void* d_out, int out_size, void* d_ws, size_t ws_size,
                              hipStream_t stream){
  const float* xyz1    = (const float*)d_in[0];
  const float* xyz2    = (const float*)d_in[1];
  const float* points1 = (const float*)d_in[2];
  const float* points2 = (const float*)d_in[3];
  const float* W1  = (const float*)d_in[4];
  const float* b1  = (const float*)d_in[5];
  const float* g1  = (const float*)d_in[6];
  const float* be1 = (const float*)d_in[7];
  const float* W2  = (const float*)d_in[8];
  const float* b2  = (const float*)d_in[9];
  const float* g2  = (const float*)d_in[10];
  const float* be2 = (const float*)d_in[11];
  float* out = (float*)d_out;

  char* ws = (char*)d_ws;
  size_t off = 0;
  auto alloc = [&](size_t bytes) -> void* {
    void* p = ws + off;
    off += (bytes + 255) & ~(size_t)255;
    return p;
  };
  short* p2Tb   = (short*)alloc((size_t)B_*S_*D_*2);   // 8 MB (bf16)
  short* Abuf   = (short*)alloc((size_t)M_*C_*2);      // 64 MB (new_points)
  short* y1     = (short*)alloc((size_t)M_*C_*2);      // 64 MB
  short* y2     = (short*)alloc((size_t)M_*C_*2);      // 64 MB
  short* W1b    = (short*)alloc((size_t)C_*K_*2);
  short* W2b    = (short*)alloc((size_t)C_*K_*2);
  float* psum   = (float*)alloc((size_t)(M_/128)*C_*4); // 1 MB
  float* psq    = (float*)alloc((size_t)(M_/128)*C_*4); // 1 MB
  float* scale1 = (float*)alloc(C_*4);
  float* shift1 = (float*)alloc(C_*4);
  float* scale2 = (float*)alloc(C_*4);
  float* shift2 = (float*)alloc(C_*4);
  (void)ws_size; (void)in_sizes; (void)n_in; (void)out_size;

  k_wcast <<<dim3((C_*K_ + 255)/256), 256, 0, stream>>>(W1, W2, W1b, W2b);
  k_tr_p2 <<<dim3(S_/64, D_/64, B_), 256, 0, stream>>>(points2, p2Tb);
  k_tr_p1 <<<dim3(N_/64, D_/64, B_), 256, 0, stream>>>(points1, Abuf);
  k_interp<<<dim3(N_/64, B_), 256, 0, stream>>>(xyz1, xyz2, p2Tb, Abuf);
  k_gemm_t<0><<<dim3((M_/128)*(C_/128)), 256, 0, stream>>>(Abuf, W1b, b1, nullptr, nullptr, y1, psum, psq);
  k_stats <<<dim3(C_), 64, 0, stream>>>(psum, psq, g1, be1, scale1, shift1);
  k_gemm_t<1><<<dim3((M_/128)*(C_/128)), 256, 0, stream>>>(y1, W2b, b2, scale1, shift1, y2, psum, psq);
  k_stats <<<dim3(C_), 64, 0, stream>>>(psum, psq, g2, be2, scale2, shift2);
  k_out   <<<dim3(M_/64, C_/64), 256, 0, stream>>>(y2, scale2, shift2, out);
}